// Round 1
// baseline (556.536 us; speedup 1.0000x reference)
//
#include <hip/hip_runtime.h>

// MLP_48687749268221: out[e] = W3 @ relu(W2 @ relu(W1 @ concat(drug[i0],dis[i1]) + b1) + b2) + b3
// E = 2e6 edges, feature dims 256 -> 128 -> 64 -> 1. bf16 MFMA, f32 accumulate.

typedef __bf16 bf16x8 __attribute__((ext_vector_type(8)));
typedef unsigned short u16x8 __attribute__((ext_vector_type(8)));
typedef float f32x4 __attribute__((ext_vector_type(4)));

static __device__ __forceinline__ unsigned short f2b(float f) {
  // f32 -> bf16 round-to-nearest-even (inputs are finite; no NaN handling needed)
  unsigned int u = __builtin_bit_cast(unsigned int, f);
  u += 0x7FFFu + ((u >> 16) & 1u);
  return (unsigned short)(u >> 16);
}

static __device__ __forceinline__ f32x4 mfma_bf16(u16x8 a, u16x8 b, f32x4 c) {
  return __builtin_amdgcn_mfma_f32_16x16x32_bf16(
      __builtin_bit_cast(bf16x8, a), __builtin_bit_cast(bf16x8, b), c, 0, 0, 0);
}

// LDS: A tile [128 rows][512 B] (256 bf16/row), XOR-swizzled. H1 [128][256 B] aliased at
// offset 0 (after barrier). partials[4][128] f32 at offset 65536.
__global__ __launch_bounds__(256, 2) void mlp_fused(
    const float* __restrict__ drug, const float* __restrict__ dis,
    const int* __restrict__ eidx, const float* __restrict__ W1,
    const float* __restrict__ b1, const float* __restrict__ W2,
    const float* __restrict__ b2, const float* __restrict__ W3,
    const float* __restrict__ b3, float* __restrict__ out, int E) {
  __shared__ __align__(16) unsigned char smem[65536 + 2048];
  unsigned char* Abase = smem;                 // A tile / later H1
  float* partials = (float*)(smem + 65536);    // [4][128]

  const int tid = threadIdx.x;
  const int w = tid >> 6;    // wave 0..3
  const int l = tid & 63;    // lane 0..63
  const int l15 = l & 15;
  const int lq = l >> 4;     // 0..3
  const int e0 = blockIdx.x * 128;

  // ---- W1 slice -> registers: wave w owns output cols [32w, 32w+32) ----
  // B-frag (16x16x32): lane l holds B[k][n], n = l&15 (+16*ntl), k = 8*(l>>4)+j (+32*kt)
  // B[k][n] = W1[n][k] (W1 row-major [128][256]) -> 8 contiguous f32 per lane.
  u16x8 w1f[2][8];
#pragma unroll
  for (int ntl = 0; ntl < 2; ++ntl) {
    const float* wrow = W1 + (32 * w + 16 * ntl + l15) * 256;
#pragma unroll
    for (int kt = 0; kt < 8; ++kt) {
      const int k0 = 32 * kt + 8 * lq;
      const float4 f0 = *(const float4*)(wrow + k0);
      const float4 f1 = *(const float4*)(wrow + k0 + 4);
      u16x8 v;
      v[0] = f2b(f0.x); v[1] = f2b(f0.y); v[2] = f2b(f0.z); v[3] = f2b(f0.w);
      v[4] = f2b(f1.x); v[5] = f2b(f1.y); v[6] = f2b(f1.z); v[7] = f2b(f1.w);
      w1f[ntl][kt] = v;
    }
  }
  // ---- W2 slice -> registers: wave w owns layer-2 cols [16w, 16w+16) ----
  u16x8 w2f[4];
  {
    const float* wrow = W2 + (16 * w + l15) * 128;
#pragma unroll
    for (int kt = 0; kt < 4; ++kt) {
      const int k0 = 32 * kt + 8 * lq;
      const float4 f0 = *(const float4*)(wrow + k0);
      const float4 f1 = *(const float4*)(wrow + k0 + 4);
      u16x8 v;
      v[0] = f2b(f0.x); v[1] = f2b(f0.y); v[2] = f2b(f0.z); v[3] = f2b(f0.w);
      v[4] = f2b(f1.x); v[5] = f2b(f1.y); v[6] = f2b(f1.z); v[7] = f2b(f1.w);
      w2f[kt] = v;
    }
  }
  float b1v0 = b1[32 * w + l15];
  float b1v1 = b1[32 * w + 16 + l15];
  float b2v = b2[16 * w + l15];
  float w3v = W3[16 * w + l15];

  // ---- gather: 2 threads per edge row; f32 -> bf16 -> swizzled LDS ----
  {
    const int r = tid >> 1;       // edge row 0..127
    const int half = tid & 1;     // 0 = drug, 1 = dis
    int e = e0 + r;
    if (e >= E) e = E - 1;
    const int idx = half ? eidx[E + e] : eidx[e];
    const float* src = (half ? dis : drug) + (long)idx * 128;
    unsigned char* rowp = Abase + r * 512;
    const int swz = (r & 7) << 4;
#pragma unroll
    for (int c = 0; c < 16; ++c) {
      const float4 f0 = *(const float4*)(src + c * 8);
      const float4 f1 = *(const float4*)(src + c * 8 + 4);
      u16x8 v;
      v[0] = f2b(f0.x); v[1] = f2b(f0.y); v[2] = f2b(f0.z); v[3] = f2b(f0.w);
      v[4] = f2b(f1.x); v[5] = f2b(f1.y); v[6] = f2b(f1.z); v[7] = f2b(f1.w);
      *(u16x8*)(rowp + ((half * 256 + c * 16) ^ swz)) = v;
    }
  }
  __syncthreads();

  // ---- layer 1: acc1[mt][ntl] over all 8 m-tiles, wave's 2 n-tiles ----
  f32x4 acc1[8][2];
#pragma unroll
  for (int mt = 0; mt < 8; ++mt) {
    acc1[mt][0] = (f32x4){0.f, 0.f, 0.f, 0.f};
    acc1[mt][1] = (f32x4){0.f, 0.f, 0.f, 0.f};
  }
#pragma unroll
  for (int kt = 0; kt < 8; ++kt) {
#pragma unroll
    for (int mt = 0; mt < 8; ++mt) {
      const int row = 16 * mt + l15;
      const int byte = (64 * kt + 16 * lq) ^ ((row & 7) << 4);
      const u16x8 a = *(const u16x8*)(Abase + row * 512 + byte);
      acc1[mt][0] = mfma_bf16(a, w1f[0][kt], acc1[mt][0]);
      acc1[mt][1] = mfma_bf16(a, w1f[1][kt], acc1[mt][1]);
    }
  }
  __syncthreads();  // all waves done READING A before H1 overwrites it

  // ---- bias + relu -> H1 bf16 in LDS [128][128], swizzled, aliased over A ----
#pragma unroll
  for (int mt = 0; mt < 8; ++mt) {
#pragma unroll
    for (int ntl = 0; ntl < 2; ++ntl) {
      const int col = 32 * w + 16 * ntl + l15;
      const float bv = ntl ? b1v1 : b1v0;
#pragma unroll
      for (int i = 0; i < 4; ++i) {
        const int row = 16 * mt + 4 * lq + i;
        float h = acc1[mt][ntl][i] + bv;
        h = h > 0.f ? h : 0.f;
        *(unsigned short*)(Abase + row * 256 + (((unsigned)col * 2) ^ ((row & 7) << 4))) = f2b(h);
      }
    }
  }
  __syncthreads();

  // ---- layer 2: K=128, wave's 1 n-tile (16 cols) ----
  f32x4 acc2[8];
#pragma unroll
  for (int mt = 0; mt < 8; ++mt) acc2[mt] = (f32x4){0.f, 0.f, 0.f, 0.f};
#pragma unroll
  for (int kt = 0; kt < 4; ++kt) {
#pragma unroll
    for (int mt = 0; mt < 8; ++mt) {
      const int row = 16 * mt + l15;
      const int byte = (64 * kt + 16 * lq) ^ ((row & 7) << 4);
      const u16x8 a = *(const u16x8*)(Abase + row * 256 + byte);
      acc2[mt] = mfma_bf16(a, w2f[kt], acc2[mt]);
    }
  }

  // ---- layer 3: relu(acc2 + b2) . W3, 16-lane shuffle reduce ----
#pragma unroll
  for (int mt = 0; mt < 8; ++mt) {
#pragma unroll
    for (int i = 0; i < 4; ++i) {
      float h = acc2[mt][i] + b2v;
      h = h > 0.f ? h : 0.f;
      float p = h * w3v;
      p += __shfl_xor(p, 1, 64);
      p += __shfl_xor(p, 2, 64);
      p += __shfl_xor(p, 4, 64);
      p += __shfl_xor(p, 8, 64);
      if (l15 == 0) partials[w * 128 + 16 * mt + 4 * lq + i] = p;
    }
  }
  __syncthreads();

  if (tid < 128) {
    const int e = e0 + tid;
    if (e < E) {
      out[e] = partials[tid] + partials[128 + tid] + partials[256 + tid] +
               partials[384 + tid] + b3[0];
    }
  }
}

extern "C" void kernel_launch(void* const* d_in, const int* in_sizes, int n_in,
                              void* d_out, int out_size, void* d_ws, size_t ws_size,
                              hipStream_t stream) {
  const float* drug = (const float*)d_in[0];
  const float* dis = (const float*)d_in[1];
  const int* eidx = (const int*)d_in[2];
  const float* W1 = (const float*)d_in[3];
  const float* b1 = (const float*)d_in[4];
  const float* W2 = (const float*)d_in[5];
  const float* b2 = (const float*)d_in[6];
  const float* W3 = (const float*)d_in[7];
  const float* b3 = (const float*)d_in[8];
  float* out = (float*)d_out;
  const int E = in_sizes[2] / 2;
  const int grid = (E + 127) / 128;
  mlp_fused<<<grid, 256, 0, stream>>>(drug, dis, eidx, W1, b1, W2, b2, W3, b3, out, E);
}

// Round 3
// 273.814 us; speedup vs baseline: 2.0325x; 2.0325x over previous
//
#include <hip/hip_runtime.h>

// MLP_48687749268221: out[e] = W3 @ relu(W2 @ relu(W1 @ concat(drug[i0],dis[i1]) + b1) + b2) + b3
// E = 2e6, dims 256 -> 128 -> 64 -> 1. bf16 MFMA, f32 accumulate.
// Round 3: round-2 design with the d_in[5] (W2) host-pointer fix.

typedef __bf16 bf16x8 __attribute__((ext_vector_type(8)));
typedef unsigned short u16x8 __attribute__((ext_vector_type(8)));
typedef float f32x4 __attribute__((ext_vector_type(4)));

static __device__ __forceinline__ unsigned short f2b(float f) {
  // f32 -> bf16 RTNE (inputs finite)
  unsigned int u = __builtin_bit_cast(unsigned int, f);
  u += 0x7FFFu + ((u >> 16) & 1u);
  return (unsigned short)(u >> 16);
}

static __device__ __forceinline__ f32x4 mfma_bf16(u16x8 a, u16x8 b, f32x4 c) {
  return __builtin_amdgcn_mfma_f32_16x16x32_bf16(
      __builtin_bit_cast(bf16x8, a), __builtin_bit_cast(bf16x8, b), c, 0, 0, 0);
}

// ---------- prologue 1: f32 tables -> bf16 tables ----------
__global__ void cvt_tables(const float* __restrict__ a, const float* __restrict__ b,
                           unsigned short* __restrict__ oa, unsigned short* __restrict__ ob,
                           int na, int nb) {
  const int t = blockIdx.x * blockDim.x + threadIdx.x;
  const int ta = na >> 3;
  const float* src;
  unsigned short* dst;
  int i;
  if (t < ta) {
    src = a; dst = oa; i = t;
  } else {
    i = t - ta;
    if (i >= (nb >> 3)) return;
    src = b; dst = ob;
  }
  const float4 f0 = *(const float4*)(src + i * 8);
  const float4 f1 = *(const float4*)(src + i * 8 + 4);
  u16x8 v;
  v[0] = f2b(f0.x); v[1] = f2b(f0.y); v[2] = f2b(f0.z); v[3] = f2b(f0.w);
  v[4] = f2b(f1.x); v[5] = f2b(f1.y); v[6] = f2b(f1.z); v[7] = f2b(f1.w);
  *(u16x8*)(dst + i * 8) = v;
}

// ---------- prologue 2: weights -> bf16 in B-fragment order ----------
// B-frag (16x16x32): lane l holds B[k][n], n = 16*nt + (l&15), k = 32*kt + 8*(l>>4) + j.
// W1 frag slot t = (nt*8 + kt)*64 + l  (nt 0..7, kt 0..7); W2: (nt*4 + kt)*64 + l (nt 0..3, kt 0..3).
__global__ void cvt_weights(const float* __restrict__ W1, const float* __restrict__ W2,
                            unsigned short* __restrict__ o1, unsigned short* __restrict__ o2) {
  const int t = blockIdx.x * blockDim.x + threadIdx.x;
  if (t < 4096) {
    const int l = t & 63, kt = (t >> 6) & 7, nt = t >> 9;
    const int n = 16 * nt + (l & 15), k0 = 32 * kt + 8 * (l >> 4);
    const float* src = W1 + n * 256 + k0;
    u16x8 v;
#pragma unroll
    for (int j = 0; j < 8; ++j) v[j] = f2b(src[j]);
    *(u16x8*)(o1 + t * 8) = v;
  } else if (t < 5120) {
    const int u = t - 4096;
    const int l = u & 63, kt = (u >> 6) & 3, nt = u >> 8;
    const int n = 16 * nt + (l & 15), k0 = 32 * kt + 8 * (l >> 4);
    const float* src = W2 + n * 128 + k0;
    u16x8 v;
#pragma unroll
    for (int j = 0; j < 8; ++j) v[j] = f2b(src[j]);
    *(u16x8*)(o2 + u * 8) = v;
  }
}

// ---------- main fused kernel ----------
// 512 threads = 8 waves (wm = w>>2 in {0,1} splits the 128 edge rows; wn = w&3 splits cols).
// LDS: A tile [128 rows][512 B] bf16 XOR-swizzled; H1 [128][256 B] aliased over A; partials[4][128] f32.
__global__ __launch_bounds__(512, 4) void mlp_fused(
    const unsigned short* __restrict__ drugB, const unsigned short* __restrict__ disB,
    const int* __restrict__ eidx, const unsigned short* __restrict__ w1frag,
    const unsigned short* __restrict__ w2frag, const float* __restrict__ b1,
    const float* __restrict__ b2, const float* __restrict__ W3,
    const float* __restrict__ b3, float* __restrict__ out, int E) {
  __shared__ __align__(16) unsigned char smem[65536 + 2048];
  unsigned char* Abase = smem;
  float* partials = (float*)(smem + 65536);

  const int tid = threadIdx.x;
  const int w = tid >> 6;
  const int wm = w >> 2;   // 0..1: edge-row half
  const int wn = w & 3;    // 0..3: col quarter
  const int l = tid & 63;
  const int l15 = l & 15;
  const int lq = l >> 4;
  const int e0 = blockIdx.x * 128;

  // ---- gather: 4 threads per edge row, bf16 tables, 64 B each ----
  {
    const int r = tid >> 2;   // row 0..127
    const int q = tid & 3;    // 0,1 = drug halves; 2,3 = dis halves
    int e = e0 + r;
    if (e >= E) e = E - 1;
    const int idx = (q < 2) ? eidx[e] : eidx[E + e];
    const unsigned short* src = ((q < 2) ? drugB : disB) + (long)idx * 128 + (q & 1) * 64;
    unsigned char* rowp = Abase + r * 512;
    const int base = q * 128;
    const int swz = (r & 7) << 4;
#pragma unroll
    for (int c = 0; c < 8; ++c) {
      const u16x8 v = *(const u16x8*)(src + c * 8);
      *(u16x8*)(rowp + ((base + c * 16) ^ swz)) = v;
    }
  }

  // ---- W2 frags resident (16 VGPR), biases ----
  u16x8 w2f[4];
#pragma unroll
  for (int kt = 0; kt < 4; ++kt)
    w2f[kt] = *(const u16x8*)(w2frag + ((wn * 4 + kt) * 64 + l) * 8);
  const float b1v0 = b1[32 * wn + l15];
  const float b1v1 = b1[32 * wn + 16 + l15];
  const float b2v = b2[16 * wn + l15];
  const float w3v = W3[16 * wn + l15];
  __syncthreads();

  // ---- layer 1: K=256, wave's 4 m-tiles x 2 n-tiles; W1 frags streamed ----
  f32x4 acc1[4][2];
#pragma unroll
  for (int mti = 0; mti < 4; ++mti) {
    acc1[mti][0] = (f32x4){0.f, 0.f, 0.f, 0.f};
    acc1[mti][1] = (f32x4){0.f, 0.f, 0.f, 0.f};
  }
  const unsigned short* w1p = w1frag + ((2 * wn) * 8 * 64 + l) * 8;  // (nt=2wn, kt=0, lane l)
  // frag (ntl, kt) at w1p + (ntl*8*64 + kt*64)*8
  u16x8 nf0 = *(const u16x8*)(w1p);
  u16x8 nf1 = *(const u16x8*)(w1p + 512 * 8);
#pragma unroll
  for (int kt = 0; kt < 8; ++kt) {
    const u16x8 c0 = nf0, c1 = nf1;
    if (kt < 7) {
      nf0 = *(const u16x8*)(w1p + (kt + 1) * 64 * 8);
      nf1 = *(const u16x8*)(w1p + (512 + (kt + 1) * 64) * 8);
    }
#pragma unroll
    for (int mti = 0; mti < 4; ++mti) {
      const int row = 16 * (4 * wm + mti) + l15;
      const u16x8 a = *(const u16x8*)(Abase + row * 512 + ((64 * kt + 16 * lq) ^ ((row & 7) << 4)));
      acc1[mti][0] = mfma_bf16(a, c0, acc1[mti][0]);
      acc1[mti][1] = mfma_bf16(a, c1, acc1[mti][1]);
    }
  }
  __syncthreads();  // everyone done READING A before H1 overwrites it

  // ---- bias+relu -> H1 bf16 [128 rows][128 cols], swizzled, aliased over A ----
#pragma unroll
  for (int mti = 0; mti < 4; ++mti) {
#pragma unroll
    for (int ntl = 0; ntl < 2; ++ntl) {
      const int col = 32 * wn + 16 * ntl + l15;
      const float bv = ntl ? b1v1 : b1v0;
#pragma unroll
      for (int i = 0; i < 4; ++i) {
        const int row = 16 * (4 * wm + mti) + 4 * lq + i;
        float h = acc1[mti][ntl][i] + bv;
        h = h > 0.f ? h : 0.f;
        *(unsigned short*)(Abase + row * 256 + (((unsigned)col * 2) ^ ((row & 7) << 4))) = f2b(h);
      }
    }
  }
  __syncthreads();

  // ---- layer 2: K=128, wave's 4 m-tiles x 1 n-tile ----
  f32x4 acc2[4];
#pragma unroll
  for (int mti = 0; mti < 4; ++mti) acc2[mti] = (f32x4){0.f, 0.f, 0.f, 0.f};
#pragma unroll
  for (int kt = 0; kt < 4; ++kt) {
#pragma unroll
    for (int mti = 0; mti < 4; ++mti) {
      const int row = 16 * (4 * wm + mti) + l15;
      const u16x8 a = *(const u16x8*)(Abase + row * 256 + ((64 * kt + 16 * lq) ^ ((row & 7) << 4)));
      acc2[mti] = mfma_bf16(a, w2f[kt], acc2[mti]);
    }
  }

  // ---- layer 3: relu(.)+b2 dot W3 slice, butterfly reduce-scatter over l15 ----
  float p[16];
#pragma unroll
  for (int mti = 0; mti < 4; ++mti)
#pragma unroll
    for (int i = 0; i < 4; ++i) {
      float h = acc2[mti][i] + b2v;
      h = h > 0.f ? h : 0.f;
      p[mti * 4 + i] = h * w3v;
    }
  float a8[8];
#pragma unroll
  for (int j = 0; j < 8; ++j) {
    const bool hi = (l15 & 1);
    const float give = hi ? p[2 * j] : p[2 * j + 1];
    const float keep = hi ? p[2 * j + 1] : p[2 * j];
    a8[j] = keep + __shfl_xor(give, 1, 64);
  }
  float a4[4];
#pragma unroll
  for (int j = 0; j < 4; ++j) {
    const bool hi = (l15 & 2);
    const float give = hi ? a8[2 * j] : a8[2 * j + 1];
    const float keep = hi ? a8[2 * j + 1] : a8[2 * j];
    a4[j] = keep + __shfl_xor(give, 2, 64);
  }
  float a2[2];
#pragma unroll
  for (int j = 0; j < 2; ++j) {
    const bool hi = (l15 & 4);
    const float give = hi ? a4[2 * j] : a4[2 * j + 1];
    const float keep = hi ? a4[2 * j + 1] : a4[2 * j];
    a2[j] = keep + __shfl_xor(give, 4, 64);
  }
  float d;
  {
    const bool hi = (l15 & 8);
    const float give = hi ? a2[0] : a2[1];
    const float keep = hi ? a2[1] : a2[0];
    d = keep + __shfl_xor(give, 8, 64);
  }
  // lane now holds the full 16-col partial for value v = l15 -> row:
  const int row = 16 * (4 * wm + (l15 >> 2)) + 4 * lq + (l15 & 3);
  partials[wn * 128 + row] = d;
  __syncthreads();

  if (tid < 128) {
    const int e = e0 + tid;
    if (e < E) {
      out[e] = partials[tid] + partials[128 + tid] + partials[256 + tid] +
               partials[384 + tid] + b3[0];
    }
  }
}

extern "C" void kernel_launch(void* const* d_in, const int* in_sizes, int n_in,
                              void* d_out, int out_size, void* d_ws, size_t ws_size,
                              hipStream_t stream) {
  const float* drug = (const float*)d_in[0];
  const float* dis = (const float*)d_in[1];
  const int* eidx = (const int*)d_in[2];
  const float* W1 = (const float*)d_in[3];
  const float* b1 = (const float*)d_in[4];
  const float* W2 = (const float*)d_in[5];
  const float* b2 = (const float*)d_in[6];
  const float* W3 = (const float*)d_in[7];
  const float* b3 = (const float*)d_in[8];
  float* out = (float*)d_out;

  const int na = in_sizes[0];           // 10000*128
  const int nb = in_sizes[1];           // 5000*128
  const int E = in_sizes[2] / 2;        // 2e6

  unsigned short* ws = (unsigned short*)d_ws;
  unsigned short* drugB = ws;
  unsigned short* disB = ws + na;
  unsigned short* w1f = ws + na + nb;
  unsigned short* w2f = w1f + 128 * 256;
  // total ws use: (na+nb)*2 + 81920 bytes ~= 3.92 MB

  const int tct = (na + nb) >> 3;
  cvt_tables<<<(tct + 255) / 256, 256, 0, stream>>>(drug, dis, drugB, disB, na, nb);
  cvt_weights<<<20, 256, 0, stream>>>(W1, W2, w1f, w2f);

  const int grid = (E + 127) / 128;
  mlp_fused<<<grid, 512, 0, stream>>>(drugB, disB, eidx, w1f, w2f, b1, b2, W3, b3, out, E);
}

// Round 4
// 245.228 us; speedup vs baseline: 2.2695x; 1.1166x over previous
//
#include <hip/hip_runtime.h>

// MLP_48687749268221: out[e] = W3 @ relu(W2 @ relu(W1 @ concat(drug[i0],dis[i1]) + b1) + b2) + b3
// E = 2e6, dims 256 -> 128 -> 64 -> 1. bf16 MFMA, f32 accumulate.
// Round 4: swapped MFMA operands (D=[units][edges]) -> H1 epilogue is 8x ds_write_b64
// instead of 32x ds_write_b16; 64-edge/256-thread blocks -> 4 blocks/CU (4 barrier groups);
// layer-3 reduce = 2 shuffles.

typedef __bf16 bf16x8 __attribute__((ext_vector_type(8)));
typedef unsigned short u16x8 __attribute__((ext_vector_type(8)));
typedef float f32x4 __attribute__((ext_vector_type(4)));

static __device__ __forceinline__ unsigned short f2b(float f) {
  // f32 -> bf16 RTNE (inputs finite)
  unsigned int u = __builtin_bit_cast(unsigned int, f);
  u += 0x7FFFu + ((u >> 16) & 1u);
  return (unsigned short)(u >> 16);
}

static __device__ __forceinline__ f32x4 mfma_bf16(u16x8 a, u16x8 b, f32x4 c) {
  return __builtin_amdgcn_mfma_f32_16x16x32_bf16(
      __builtin_bit_cast(bf16x8, a), __builtin_bit_cast(bf16x8, b), c, 0, 0, 0);
}

// ---------- prologue 1: f32 tables -> bf16 tables ----------
__global__ void cvt_tables(const float* __restrict__ a, const float* __restrict__ b,
                           unsigned short* __restrict__ oa, unsigned short* __restrict__ ob,
                           int na, int nb) {
  const int t = blockIdx.x * blockDim.x + threadIdx.x;
  const int ta = na >> 3;
  const float* src;
  unsigned short* dst;
  int i;
  if (t < ta) {
    src = a; dst = oa; i = t;
  } else {
    i = t - ta;
    if (i >= (nb >> 3)) return;
    src = b; dst = ob;
  }
  const float4 f0 = *(const float4*)(src + i * 8);
  const float4 f1 = *(const float4*)(src + i * 8 + 4);
  u16x8 v;
  v[0] = f2b(f0.x); v[1] = f2b(f0.y); v[2] = f2b(f0.z); v[3] = f2b(f0.w);
  v[4] = f2b(f1.x); v[5] = f2b(f1.y); v[6] = f2b(f1.z); v[7] = f2b(f1.w);
  *(u16x8*)(dst + i * 8) = v;
}

// ---------- prologue 2: weights -> bf16 in fragment order ----------
// Frag (16x16x32): lane l holds elem[dim][k], dim = 16*t + (l&15), k = 32*kt + 8*(l>>4) + j.
// W1 slot t = (ut*8 + kt)*64 + l  (ut 0..7, kt 0..7); W2: (nt2*4 + kt)*64 + l (nt2 0..3, kt 0..3).
__global__ void cvt_weights(const float* __restrict__ W1, const float* __restrict__ W2,
                            unsigned short* __restrict__ o1, unsigned short* __restrict__ o2) {
  const int t = blockIdx.x * blockDim.x + threadIdx.x;
  if (t < 4096) {
    const int l = t & 63, kt = (t >> 6) & 7, ut = t >> 9;
    const int n = 16 * ut + (l & 15), k0 = 32 * kt + 8 * (l >> 4);
    const float* src = W1 + n * 256 + k0;
    u16x8 v;
#pragma unroll
    for (int j = 0; j < 8; ++j) v[j] = f2b(src[j]);
    *(u16x8*)(o1 + t * 8) = v;
  } else if (t < 5120) {
    const int u = t - 4096;
    const int l = u & 63, kt = (u >> 6) & 3, nt = u >> 8;
    const int n = 16 * nt + (l & 15), k0 = 32 * kt + 8 * (l >> 4);
    const float* src = W2 + n * 128 + k0;
    u16x8 v;
#pragma unroll
    for (int j = 0; j < 8; ++j) v[j] = f2b(src[j]);
    *(u16x8*)(o2 + u * 8) = v;
  }
}

// ---------- main fused kernel ----------
// 256 threads = 4 waves; wave wn owns W1 units [32wn,32wn+32) and W2 units [16wn,16wn+16).
// Tile = 64 edges. LDS: A [64 rows][512 B] bf16 swizzled; H1 [64][256 B] aliased over A;
// partials [4][64] f32. ~33.8 KB -> 4 blocks/CU.
__global__ __launch_bounds__(256, 4) void mlp_fused(
    const unsigned short* __restrict__ drugB, const unsigned short* __restrict__ disB,
    const int* __restrict__ eidx, const unsigned short* __restrict__ w1frag,
    const unsigned short* __restrict__ w2frag, const float* __restrict__ b1,
    const float* __restrict__ b2, const float* __restrict__ W3,
    const float* __restrict__ b3, float* __restrict__ out, int E) {
  __shared__ __align__(16) unsigned char smem[32768 + 1024];
  unsigned char* Abase = smem;
  float* partials = (float*)(smem + 32768);

  const int tid = threadIdx.x;
  const int wn = tid >> 6;   // wave 0..3: unit-column quarter
  const int l = tid & 63;
  const int l15 = l & 15;
  const int lq = l >> 4;
  const int e0 = blockIdx.x * 64;

  // ---- gather: 4 threads per edge row, bf16 tables, 128 B each ----
  {
    const int r = tid >> 2;   // row 0..63
    const int q = tid & 3;    // 0,1 = drug halves; 2,3 = dis halves
    int e = e0 + r;
    if (e >= E) e = E - 1;
    const int idx = (q < 2) ? eidx[e] : eidx[E + e];
    const unsigned short* src = ((q < 2) ? drugB : disB) + (long)idx * 128 + (q & 1) * 64;
    unsigned char* rowp = Abase + r * 512;
    const int base = q * 128;
    const int swz = (r & 7) << 4;
#pragma unroll
    for (int c = 0; c < 8; ++c) {
      const u16x8 v = *(const u16x8*)(src + c * 8);
      *(u16x8*)(rowp + ((base + c * 16) ^ swz)) = v;
    }
  }

  // ---- W2 A-frags resident, bias/W3 float4 per lane ----
  u16x8 w2f[4];
#pragma unroll
  for (int kt = 0; kt < 4; ++kt)
    w2f[kt] = *(const u16x8*)(w2frag + ((wn * 4 + kt) * 64 + l) * 8);
  const float4 b1v0 = *(const float4*)(b1 + 32 * wn + 4 * lq);
  const float4 b1v1 = *(const float4*)(b1 + 32 * wn + 16 + 4 * lq);
  const float4 b2v = *(const float4*)(b2 + 16 * wn + 4 * lq);
  const float4 w3v = *(const float4*)(W3 + 16 * wn + 4 * lq);
  __syncthreads();

  // ---- layer 1: D1[unit][edge]; A = W1 frags (streamed), B = edge frags from LDS ----
  f32x4 acc1[2][4];
#pragma unroll
  for (int uti = 0; uti < 2; ++uti)
#pragma unroll
    for (int nt = 0; nt < 4; ++nt) acc1[uti][nt] = (f32x4){0.f, 0.f, 0.f, 0.f};

  const unsigned short* w1p = w1frag + ((2 * wn) * 512 + l) * 8;  // ut = 2wn, kt = 0
  u16x8 nf0 = *(const u16x8*)(w1p);
  u16x8 nf1 = *(const u16x8*)(w1p + 512 * 8);
#pragma unroll
  for (int kt = 0; kt < 8; ++kt) {
    const u16x8 c0 = nf0, c1 = nf1;
    if (kt < 7) {
      nf0 = *(const u16x8*)(w1p + (kt + 1) * 64 * 8);
      nf1 = *(const u16x8*)(w1p + (512 + (kt + 1) * 64) * 8);
    }
#pragma unroll
    for (int nt = 0; nt < 4; ++nt) {
      const int e = 16 * nt + l15;
      const u16x8 b = *(const u16x8*)(Abase + e * 512 + ((64 * kt + 16 * lq) ^ ((e & 7) << 4)));
      acc1[0][nt] = mfma_bf16(c0, b, acc1[0][nt]);
      acc1[1][nt] = mfma_bf16(c1, b, acc1[1][nt]);
    }
  }
  __syncthreads();  // all waves done reading A before H1 overwrites it

  // ---- H1 epilogue: bias+relu, pack 4 bf16 (consecutive units) -> ds_write_b64 ----
  // H1 layout [edge][unit]: addr = e*256 + ((64wn + 32uti + 8lq) ^ ((e&7)<<4))
#pragma unroll
  for (int uti = 0; uti < 2; ++uti) {
    const float4 bv = uti ? b1v1 : b1v0;
#pragma unroll
    for (int nt = 0; nt < 4; ++nt) {
      const int e = 16 * nt + l15;
      float h0 = acc1[uti][nt][0] + bv.x; h0 = h0 > 0.f ? h0 : 0.f;
      float h1 = acc1[uti][nt][1] + bv.y; h1 = h1 > 0.f ? h1 : 0.f;
      float h2 = acc1[uti][nt][2] + bv.z; h2 = h2 > 0.f ? h2 : 0.f;
      float h3 = acc1[uti][nt][3] + bv.w; h3 = h3 > 0.f ? h3 : 0.f;
      ushort4 hv;
      hv.x = f2b(h0); hv.y = f2b(h1); hv.z = f2b(h2); hv.w = f2b(h3);
      *(ushort4*)(Abase + e * 256 + ((64 * wn + 32 * uti + 8 * lq) ^ ((e & 7) << 4))) = hv;
    }
  }
  __syncthreads();

  // ---- layer 2: D2[n2][edge]; A = W2 frags, B = H1 frags from LDS ----
  f32x4 acc2[4];
#pragma unroll
  for (int nt = 0; nt < 4; ++nt) acc2[nt] = (f32x4){0.f, 0.f, 0.f, 0.f};
#pragma unroll
  for (int kt = 0; kt < 4; ++kt) {
#pragma unroll
    for (int nt = 0; nt < 4; ++nt) {
      const int e = 16 * nt + l15;
      const u16x8 b = *(const u16x8*)(Abase + e * 256 + ((64 * kt + 16 * lq) ^ ((e & 7) << 4)));
      acc2[nt] = mfma_bf16(w2f[kt], b, acc2[nt]);
    }
  }

  // ---- layer 3: relu(.+b2) dot W3 (4 units per lane), reduce over lq with 2 shuffles ----
#pragma unroll
  for (int nt = 0; nt < 4; ++nt) {
    float h0 = acc2[nt][0] + b2v.x; h0 = h0 > 0.f ? h0 : 0.f;
    float h1 = acc2[nt][1] + b2v.y; h1 = h1 > 0.f ? h1 : 0.f;
    float h2 = acc2[nt][2] + b2v.z; h2 = h2 > 0.f ? h2 : 0.f;
    float h3 = acc2[nt][3] + b2v.w; h3 = h3 > 0.f ? h3 : 0.f;
    float s = h0 * w3v.x + h1 * w3v.y + h2 * w3v.z + h3 * w3v.w;
    s += __shfl_xor(s, 16, 64);
    s += __shfl_xor(s, 32, 64);
    if (l < 16) partials[wn * 64 + 16 * nt + l15] = s;
  }
  __syncthreads();

  if (tid < 64) {
    const int e = e0 + tid;
    if (e < E) {
      out[e] = partials[tid] + partials[64 + tid] + partials[128 + tid] +
               partials[192 + tid] + b3[0];
    }
  }
}

extern "C" void kernel_launch(void* const* d_in, const int* in_sizes, int n_in,
                              void* d_out, int out_size, void* d_ws, size_t ws_size,
                              hipStream_t stream) {
  const float* drug = (const float*)d_in[0];
  const float* dis = (const float*)d_in[1];
  const int* eidx = (const int*)d_in[2];
  const float* W1 = (const float*)d_in[3];
  const float* b1 = (const float*)d_in[4];
  const float* W2 = (const float*)d_in[5];
  const float* b2 = (const float*)d_in[6];
  const float* W3 = (const float*)d_in[7];
  const float* b3 = (const float*)d_in[8];
  float* out = (float*)d_out;

  const int na = in_sizes[0];           // 10000*128
  const int nb = in_sizes[1];           // 5000*128
  const int E = in_sizes[2] / 2;        // 2e6

  unsigned short* ws = (unsigned short*)d_ws;
  unsigned short* drugB = ws;
  unsigned short* disB = ws + na;
  unsigned short* w1f = ws + na + nb;
  unsigned short* w2f = w1f + 128 * 256;
  // total ws use: (na+nb)*2 + 81920 bytes ~= 3.92 MB

  const int tct = (na + nb) >> 3;
  cvt_tables<<<(tct + 255) / 256, 256, 0, stream>>>(drug, dis, drugB, disB, na, nb);
  cvt_weights<<<20, 256, 0, stream>>>(W1, W2, w1f, w2f);

  const int grid = (E + 63) / 64;
  mlp_fused<<<grid, 256, 0, stream>>>(drugB, disB, eidx, w1f, w2f, b1, b2, W3, b3, out, E);
}